// Round 14
// baseline (391.238 us; speedup 1.0000x reference)
//
#include <hip/hip_runtime.h>

#define CC   256
#define DHWC 65536          // D*H*W
#define NBC  2              // batch

typedef __attribute__((ext_vector_type(8))) short bf16x8;
typedef __attribute__((ext_vector_type(4))) short bf16x4;
typedef __attribute__((ext_vector_type(4))) float f32x4;

// ---- bf16 split helpers (branchless, bit-level, RTN-even) --------------------
__device__ __forceinline__ short f2bf(float x) {
    unsigned u = __builtin_bit_cast(unsigned, x);
    unsigned r = (u + 0x7fffu + ((u >> 16) & 1u)) >> 16;
    return (short)r;
}
__device__ __forceinline__ float bf2f(short h) {
    unsigned u = ((unsigned)(unsigned short)h) << 16;
    return __builtin_bit_cast(float, u);
}
// pack value into u32: low16 = bf16 hi, high16 = bf16 lo (bit-identical split)
__device__ __forceinline__ unsigned packsplit(float val) {
    const short h = f2bf(val);
    const short l = f2bf(val - bf2f(h));
    return (unsigned)(unsigned short)h | ((unsigned)(unsigned short)l << 16);
}

// swizzled byte offset into a [R rows][64 c] bf16 LDS plane (row stride 128 B).
__device__ __forceinline__ int swz(int r, int c) {
    return (r * 128 + c * 2) ^ ((r & 7) << 4);
}
// richer swizzle for the V^T plane (write pattern is rows at stride 4)
__device__ __forceinline__ int vswz(int r, int c) {
    return (r * 128 + c * 2) ^ (((r ^ (r >> 3)) & 7) << 4);
}
// swizzled byte offset into a [128 s][256 k] bf16 LDS plane (row stride 512 B).
__device__ __forceinline__ int swz512(int s, int k) {
    return (s * 512 + k * 2) ^ ((s & 7) << 4);
}
// swizzled byte offset into a [256 rows][128 s] bf16 bounce plane (stride 256 B).
__device__ __forceinline__ int swz256(int r, int s) {
    return (r * 256 + s * 2) ^ ((r & 7) << 4);
}
// swizzled byte offset into a [128 rows][128 c] 4B-elem bounce plane (stride 512 B).
__device__ __forceinline__ int swzf(int r, int c) {
    return (r * 512 + c * 4) ^ ((r & 7) << 4);
}

// ---------------------------------------------------------------------------
// prep: split 5 weight matrices [256][256] fp32 into hi/lo bf16 planes stored
// fragment-major for mfma_f32_16x16x32_bf16 A-operand. Matrix m: hi at
// wsp + m*131072, lo at +65536.
// ---------------------------------------------------------------------------
__global__ void prep_w_kernel(const float* __restrict__ q_w, const float* __restrict__ k_w,
                              const float* __restrict__ v_w, const float* __restrict__ attn_w,
                              const float* __restrict__ out_w, short* __restrict__ wsp)
{
    const int l  = threadIdx.x;          // 64
    const int fo = blockIdx.x;           // 16
    const int t  = blockIdx.y;           // 8
    const int m  = blockIdx.z;           // 5
    const float* w = (m == 0) ? q_w : (m == 1) ? k_w : (m == 2) ? v_w
                   : (m == 3) ? attn_w : out_w;
    short* whi = wsp + (size_t)m * 131072;
    short* wlo = whi + 65536;

    const int o = fo * 16 + (l & 15);
    const int k = t * 32 + (l >> 4) * 8;

    bf16x8 hv, lv;
    #pragma unroll
    for (int r = 0; r < 8; ++r) {
        const float x = w[o * 256 + k + r];
        const short h = f2bf(x);
        hv[r] = h;
        lv[r] = f2bf(x - bf2f(h));
    }
    const int idx = (fo * 8 + t) * 64 + l;
    *(bf16x8*)(whi + idx * 8) = hv;
    *(bf16x8*)(wlo + idx * 8) = lv;
}

// ---------------------------------------------------------------------------
// conv1x1 (q), BN=128, 1024 thr = 16 waves, M=16 x N=128 wave tile.
// Output: PACKED u32 (hi|lo bf16) via one swzf 2-half LDS bounce (coalesced).
// ---------------------------------------------------------------------------
__global__ __launch_bounds__(1024, 4) void conv_mfma_kernel(
    const float* __restrict__ x, const short* __restrict__ whi,
    const short* __restrict__ wlo, const float* __restrict__ bias,
    unsigned* __restrict__ opk)
{
    __shared__ char lds[65536];

    const int tid  = threadIdx.x;
    const int lane = tid & 63;
    const int wave = tid >> 6;            // 0..15
    const size_t boff = (size_t)blockIdx.y * ((size_t)CC * DHWC);
    const int sT = blockIdx.x * 128;
    const float* xb = x + boff + sT;
    const bf16x8* whf = (const bf16x8*)whi;
    const bf16x8* wlf = (const bf16x8*)wlo;

    f32x4 acc[8];
    #pragma unroll
    for (int j = 0; j < 8; ++j) acc[j] = (f32x4){0.f, 0.f, 0.f, 0.f};

    const int s_l = tid & 127;
    const int k8  = tid >> 7;     // 0..7

    float xr[8];
    #pragma unroll
    for (int r = 0; r < 8; ++r)
        xr[r] = xb[(size_t)(k8 * 8 + r) * DHWC + s_l];
    {
        bf16x8 hv, lv;
        #pragma unroll
        for (int r = 0; r < 8; ++r) {
            const short h = f2bf(xr[r]);
            hv[r] = h;
            lv[r] = f2bf(xr[r] - bf2f(h));
        }
        const int off = swz(s_l, k8 * 8);
        *(bf16x8*)(lds + off) = hv;
        *(bf16x8*)(lds + 16384 + off) = lv;
    }

    #pragma unroll
    for (int t = 0; t < 4; ++t) {
        if (t < 3) {
            #pragma unroll
            for (int r = 0; r < 8; ++r)
                xr[r] = xb[(size_t)((t + 1) * 64 + k8 * 8 + r) * DHWC + s_l];
        }
        __syncthreads();

        const char* bhib = lds + (t & 1) * 32768;
        const char* blob = bhib + 16384;
        #pragma unroll
        for (int kk = 0; kk < 2; ++kk) {
            const int idx = (wave * 8 + 2 * t + kk) * 64 + lane;
            const bf16x8 a1h = whf[idx];
            const bf16x8 a1l = wlf[idx];
            #pragma unroll
            for (int j = 0; j < 8; ++j) {
                const int s = j * 16 + (lane & 15);
                const int k = kk * 32 + (lane >> 4) * 8;
                const bf16x8 bh = *(const bf16x8*)(bhib + swz(s, k));
                const bf16x8 bl = *(const bf16x8*)(blob + swz(s, k));
                f32x4 c = acc[j];
                c = __builtin_amdgcn_mfma_f32_16x16x32_bf16(a1h, bh, c, 0, 0, 0);
                c = __builtin_amdgcn_mfma_f32_16x16x32_bf16(a1h, bl, c, 0, 0, 0);
                c = __builtin_amdgcn_mfma_f32_16x16x32_bf16(a1l, bh, c, 0, 0, 0);
                acc[j] = c;
            }
        }

        if (t < 3) {
            bf16x8 hv, lv;
            #pragma unroll
            for (int r = 0; r < 8; ++r) {
                const short h = f2bf(xr[r]);
                hv[r] = h;
                lv[r] = f2bf(xr[r] - bf2f(h));
            }
            const int off = ((t + 1) & 1) * 32768 + swz(s_l, k8 * 8);
            *(bf16x8*)(lds + off) = hv;
            *(bf16x8*)(lds + 16384 + off) = lv;
        }
    }

    // ---- epilogue: packed u32 via LDS bounce, 2 halves of 128 rows ----
    unsigned* ob = opk + boff + sT;
    const int n_l = lane & 15;
    const int m4  = (lane >> 4) * 4;
    #pragma unroll
    for (int h = 0; h < 2; ++h) {
        __syncthreads();
        if ((wave >> 3) == h) {
            #pragma unroll
            for (int r = 0; r < 4; ++r) {
                const int o = wave * 16 + m4 + r;
                const float bv = bias[o];
                const int lr = o & 127;
                #pragma unroll
                for (int j = 0; j < 8; ++j)
                    *(unsigned*)(lds + swzf(lr, j * 16 + n_l)) = packsplit(acc[j][r] + bv);
            }
        }
        __syncthreads();
        #pragma unroll
        for (int it = 0; it < 4; ++it) {
            const int lr = it * 32 + (tid >> 5);
            const int c4 = (tid & 31) * 4;
            const uint4 vv = *(const uint4*)(lds + swzf(lr, c4));
            *(uint4*)(ob + (size_t)(h * 128 + lr) * DHWC + c4) = vv;
        }
    }
}

// ---------------------------------------------------------------------------
// kv conv, BN=128, M=16 x N=128. k -> packed u32 (one swzf bounce);
// v -> bf16 shorts (swz256 bounce).
// ---------------------------------------------------------------------------
__global__ __launch_bounds__(1024, 4) void kv_conv_kernel(
    const float* __restrict__ img,
    const short* __restrict__ wkhi, const short* __restrict__ wklo,
    const short* __restrict__ wvhi, const short* __restrict__ wvlo,
    const float* __restrict__ kb, const float* __restrict__ vb,
    unsigned* __restrict__ kpk, short* __restrict__ vout)
{
    __shared__ char lds[65536];

    const int tid  = threadIdx.x;
    const int lane = tid & 63;
    const int wave = tid >> 6;
    const size_t boff = (size_t)blockIdx.y * ((size_t)CC * DHWC);
    const int sT = blockIdx.x * 128;
    const float* xb = img + boff + sT;
    const bf16x8* wkhf = (const bf16x8*)wkhi;
    const bf16x8* wklf = (const bf16x8*)wklo;
    const bf16x8* wvhf = (const bf16x8*)wvhi;
    const bf16x8* wvlf = (const bf16x8*)wvlo;

    f32x4 acck[8], accv[8];
    #pragma unroll
    for (int j = 0; j < 8; ++j) {
        acck[j] = (f32x4){0.f, 0.f, 0.f, 0.f};
        accv[j] = (f32x4){0.f, 0.f, 0.f, 0.f};
    }

    const int s_l = tid & 127;
    const int k8  = tid >> 7;

    float xr[8];
    #pragma unroll
    for (int r = 0; r < 8; ++r)
        xr[r] = xb[(size_t)(k8 * 8 + r) * DHWC + s_l];
    {
        bf16x8 hv, lv;
        #pragma unroll
        for (int r = 0; r < 8; ++r) {
            const short h = f2bf(xr[r]);
            hv[r] = h;
            lv[r] = f2bf(xr[r] - bf2f(h));
        }
        const int off = swz(s_l, k8 * 8);
        *(bf16x8*)(lds + off) = hv;
        *(bf16x8*)(lds + 16384 + off) = lv;
    }

    #pragma unroll
    for (int t = 0; t < 4; ++t) {
        if (t < 3) {
            #pragma unroll
            for (int r = 0; r < 8; ++r)
                xr[r] = xb[(size_t)((t + 1) * 64 + k8 * 8 + r) * DHWC + s_l];
        }
        __syncthreads();

        const char* bhib = lds + (t & 1) * 32768;
        const char* blob = bhib + 16384;
        #pragma unroll
        for (int kk = 0; kk < 2; ++kk) {
            const int idx = (wave * 8 + 2 * t + kk) * 64 + lane;
            const bf16x8 akh = wkhf[idx];
            const bf16x8 akl = wklf[idx];
            const bf16x8 avh = wvhf[idx];
            const bf16x8 avl = wvlf[idx];
            #pragma unroll
            for (int j = 0; j < 8; ++j) {
                const int s = j * 16 + (lane & 15);
                const int k = kk * 32 + (lane >> 4) * 8;
                const bf16x8 bh = *(const bf16x8*)(bhib + swz(s, k));
                const bf16x8 bl = *(const bf16x8*)(blob + swz(s, k));
                f32x4 c = acck[j];
                c = __builtin_amdgcn_mfma_f32_16x16x32_bf16(akh, bh, c, 0, 0, 0);
                c = __builtin_amdgcn_mfma_f32_16x16x32_bf16(akh, bl, c, 0, 0, 0);
                c = __builtin_amdgcn_mfma_f32_16x16x32_bf16(akl, bh, c, 0, 0, 0);
                acck[j] = c;
                f32x4 d = accv[j];
                d = __builtin_amdgcn_mfma_f32_16x16x32_bf16(avh, bh, d, 0, 0, 0);
                d = __builtin_amdgcn_mfma_f32_16x16x32_bf16(avh, bl, d, 0, 0, 0);
                d = __builtin_amdgcn_mfma_f32_16x16x32_bf16(avl, bh, d, 0, 0, 0);
                accv[j] = d;
            }
        }

        if (t < 3) {
            bf16x8 hv, lv;
            #pragma unroll
            for (int r = 0; r < 8; ++r) {
                const short h = f2bf(xr[r]);
                hv[r] = h;
                lv[r] = f2bf(xr[r] - bf2f(h));
            }
            const int off = ((t + 1) & 1) * 32768 + swz(s_l, k8 * 8);
            *(bf16x8*)(lds + off) = hv;
            *(bf16x8*)(lds + 16384 + off) = lv;
        }
    }

    const int n_l = lane & 15;
    const int m4  = (lane >> 4) * 4;

    // ---- k epilogue: packed u32 via LDS bounce, 2 halves of 128 rows ----
    unsigned* ko = kpk + boff + sT;
    #pragma unroll
    for (int h = 0; h < 2; ++h) {
        __syncthreads();
        if ((wave >> 3) == h) {
            #pragma unroll
            for (int r = 0; r < 4; ++r) {
                const int o = wave * 16 + m4 + r;
                const float kbv = kb[o];
                const int lr = o & 127;
                #pragma unroll
                for (int j = 0; j < 8; ++j)
                    *(unsigned*)(lds + swzf(lr, j * 16 + n_l)) = packsplit(acck[j][r] + kbv);
            }
        }
        __syncthreads();
        #pragma unroll
        for (int it = 0; it < 4; ++it) {
            const int lr = it * 32 + (tid >> 5);
            const int c4 = (tid & 31) * 4;
            const uint4 vv = *(const uint4*)(lds + swzf(lr, c4));
            *(uint4*)(ko + (size_t)(h * 128 + lr) * DHWC + c4) = vv;
        }
    }

    // ---- v epilogue: LDS bounce -> 256B-contiguous short stores ----
    __syncthreads();
    #pragma unroll
    for (int r = 0; r < 4; ++r) {
        const int o = wave * 16 + m4 + r;
        const float vbv = vb[o];
        #pragma unroll
        for (int j = 0; j < 8; ++j)
            *(short*)(lds + swz256(o, j * 16 + n_l)) = f2bf(accv[j][r] + vbv);
    }
    __syncthreads();
    short* vo = vout + boff + sT;
    #pragma unroll
    for (int it = 0; it < 4; ++it) {
        const int row = it * 64 + wave * 4 + (lane >> 4);
        const int sc  = (lane & 15) * 8;        // 8 shorts = 16B
        const bf16x8 v8 = *(const bf16x8*)(lds + swz256(row, sc));
        *(bf16x8*)(vo + (size_t)row * DHWC + sc) = v8;
    }
}

// ---------------------------------------------------------------------------
// attention. One block (256 thr = 4 waves) per (b,c,d) slab.
// q,k arrive PACKED u32 (hi|lo) -> staging = 1 uint4 load + 2 bit-ops/elem.
// wv (bf16 hi) written IN-PLACE over the slab's k storage (k fully staged;
// slabs disjoint) -> slab layout for tail.
// ---------------------------------------------------------------------------
__global__ __launch_bounds__(256, 4) void attn_mfma_kernel(
    const unsigned* __restrict__ qpk, const unsigned* kpk,
    const short* __restrict__ vsh, short* wvk)
{
    __shared__ char lds[40960];
    const int QHI = 0, QLO = 8192, KHI = 16384, KLO = 24576, VT = 32768;

    const int tid  = threadIdx.x;
    const int lane = tid & 63;
    const int wsx  = tid >> 6;           // wave 0..3
    const size_t base = (size_t)blockIdx.x * 4096;

    {
        const unsigned* qpl = qpk + base;
        const unsigned* kpl = kpk + base;
        #pragma unroll
        for (int it = 0; it < 4; ++it) {
            const int r = it * 16 + (tid >> 4);
            const int c = (tid & 15) * 4;
            const uint4 qu = *(const uint4*)(qpl + r * 64 + c);
            const uint4 ku = *(const uint4*)(kpl + r * 64 + c);
            bf16x4 qh4, ql4, kh4, kl4;
            qh4[0] = (short)qu.x; ql4[0] = (short)(qu.x >> 16);
            qh4[1] = (short)qu.y; ql4[1] = (short)(qu.y >> 16);
            qh4[2] = (short)qu.z; ql4[2] = (short)(qu.z >> 16);
            qh4[3] = (short)qu.w; ql4[3] = (short)(qu.w >> 16);
            kh4[0] = (short)ku.x; kl4[0] = (short)(ku.x >> 16);
            kh4[1] = (short)ku.y; kl4[1] = (short)(ku.y >> 16);
            kh4[2] = (short)ku.z; kl4[2] = (short)(ku.z >> 16);
            kh4[3] = (short)ku.w; kl4[3] = (short)(ku.w >> 16);
            const int off = swz(r, c);
            *(bf16x4*)(lds + QHI + off) = qh4;
            *(bf16x4*)(lds + QLO + off) = ql4;
            *(bf16x4*)(lds + KHI + off) = kh4;
            *(bf16x4*)(lds + KLO + off) = kl4;
        }
        const short* vpl = vsh + base;
        const int x0 = (tid >> 4) * 4;
        const int w0 = (tid & 15) * 4;
        bf16x4 vr[4];
        #pragma unroll
        for (int i = 0; i < 4; ++i)
            vr[i] = *(const bf16x4*)(vpl + (x0 + i) * 64 + w0);
        #pragma unroll
        for (int j = 0; j < 4; ++j) {
            bf16x4 tv;
            #pragma unroll
            for (int i = 0; i < 4; ++i) tv[i] = vr[i][j];
            *(bf16x4*)(lds + VT + vswz(w0 + j, x0)) = tv;
        }
    }
    __syncthreads();

    f32x4 acc[4];
    #pragma unroll
    for (int j = 0; j < 4; ++j) acc[j] = (f32x4){0.f, 0.f, 0.f, 0.f};

    const int arow = wsx * 16 + (lane & 15);
    #pragma unroll
    for (int kk = 0; kk < 2; ++kk) {
        const int kcol = kk * 32 + (lane >> 4) * 8;
        const bf16x8 aqh = *(const bf16x8*)(lds + QHI + swz(arow, kcol));
        const bf16x8 aql = *(const bf16x8*)(lds + QLO + swz(arow, kcol));
        #pragma unroll
        for (int j = 0; j < 4; ++j) {
            const int brow = j * 16 + (lane & 15);
            const bf16x8 bkh = *(const bf16x8*)(lds + KHI + swz(brow, kcol));
            const bf16x8 bkl = *(const bf16x8*)(lds + KLO + swz(brow, kcol));
            f32x4 c = acc[j];
            c = __builtin_amdgcn_mfma_f32_16x16x32_bf16(aqh, bkh, c, 0, 0, 0);
            c = __builtin_amdgcn_mfma_f32_16x16x32_bf16(aqh, bkl, c, 0, 0, 0);
            c = __builtin_amdgcn_mfma_f32_16x16x32_bf16(aql, bkh, c, 0, 0, 0);
            acc[j] = c;
        }
    }

    float p[4][4], invs[4];
    #pragma unroll
    for (int r = 0; r < 4; ++r) {
        float m = fmaxf(fmaxf(acc[0][r], acc[1][r]), fmaxf(acc[2][r], acc[3][r]));
        m = fmaxf(m, __shfl_xor(m, 1));
        m = fmaxf(m, __shfl_xor(m, 2));
        m = fmaxf(m, __shfl_xor(m, 4));
        m = fmaxf(m, __shfl_xor(m, 8));
        float s = 0.f;
        #pragma unroll
        for (int j = 0; j < 4; ++j) { p[j][r] = __expf(acc[j][r] - m); s += p[j][r]; }
        s += __shfl_xor(s, 1);
        s += __shfl_xor(s, 2);
        s += __shfl_xor(s, 4);
        s += __shfl_xor(s, 8);
        invs[r] = 1.f / s;
    }

    __syncthreads();

    #pragma unroll
    for (int r = 0; r < 4; ++r) {
        const int row = wsx * 16 + (lane >> 4) * 4 + r;
        #pragma unroll
        for (int j = 0; j < 4; ++j) {
            const int col = j * 16 + (lane & 15);
            *(short*)(lds + QHI + swz(row, col)) = f2bf(p[j][r]);
        }
    }
    __syncthreads();

    f32x4 o_[4];
    #pragma unroll
    for (int j = 0; j < 4; ++j) o_[j] = (f32x4){0.f, 0.f, 0.f, 0.f};

    #pragma unroll
    for (int kk = 0; kk < 2; ++kk) {
        const int kcol = kk * 32 + (lane >> 4) * 8;
        const bf16x8 aph = *(const bf16x8*)(lds + QHI + swz(arow, kcol));
        #pragma unroll
        for (int j = 0; j < 4; ++j) {
            const int brow = j * 16 + (lane & 15);
            const bf16x8 bvh = *(const bf16x8*)(lds + VT + vswz(brow, kcol));
            o_[j] = __builtin_amdgcn_mfma_f32_16x16x32_bf16(aph, bvh, o_[j], 0, 0, 0);
        }
    }

    // ---- epilogue: wv bf16 shorts -> bounce via QHI plane -> k slab ----
    __syncthreads();
    #pragma unroll
    for (int r = 0; r < 4; ++r) {
        const int h = wsx * 16 + (lane >> 4) * 4 + r;
        #pragma unroll
        for (int j = 0; j < 4; ++j)
            *(short*)(lds + QHI + swz(h, j * 16 + (lane & 15))) = f2bf(o_[j][r] * invs[r]);
    }
    __syncthreads();
    short* wvo = wvk + (size_t)blockIdx.x * 8192;   // slab owns 8192 shorts of kpk
    #pragma unroll
    for (int it = 0; it < 4; ++it) {
        const int row = it * 16 + (tid >> 4);
        const int sc  = (tid & 15) * 4;             // 4 shorts = 8B
        const bf16x4 v4 = *(const bf16x4*)(lds + QHI + swz(row, sc));
        *(bf16x4*)(wvo + (size_t)row * 64 + sc) = v4;
    }
}

// ---------------------------------------------------------------------------
// fused tail: out = relu(W2 * relu(W1 * wv + b1) + b2). wv arrives as bf16
// shorts in SLAB layout inside kpk: element (b,c,sp) at short index
// b*33554432 + c*131072 + (sp>>12)*8192 + (sp&4095). Hi-only staging,
// 2-MFMA GEMM1; phase B hi-only a; 2-MFMA GEMM2; direct-store epilogue.
// ---------------------------------------------------------------------------
__global__ __launch_bounds__(1024, 4) void tail_fused_kernel(
    const short* __restrict__ xs,
    const short* __restrict__ w1hi, const short* __restrict__ w1lo,
    const float* __restrict__ b1,
    const short* __restrict__ w2hi, const short* __restrict__ w2lo,
    const float* __restrict__ b2,
    float* __restrict__ out)
{
    __shared__ char lds[65536];

    const int tid  = threadIdx.x;
    const int lane = tid & 63;
    const int wave = tid >> 6;
    const size_t boff = (size_t)blockIdx.y * ((size_t)CC * DHWC);
    const int sT = blockIdx.x * 128;
    const bf16x8* w1hf = (const bf16x8*)w1hi;
    const bf16x8* w1lf = (const bf16x8*)w1lo;

    f32x4 acc[8];
    #pragma unroll
    for (int j = 0; j < 8; ++j) acc[j] = (f32x4){0.f, 0.f, 0.f, 0.f};

    const int s_l = tid & 127;
    const int k8  = tid >> 7;

    // slab-layout base for this (batch, spatial tile): channel stride 131072
    const short* xslab = xs + (size_t)blockIdx.y * 33554432
                            + (size_t)(sT >> 12) * 8192 + (sT & 4095);

    short sr[8];
    #pragma unroll
    for (int r = 0; r < 8; ++r)
        sr[r] = xslab[(size_t)(k8 * 8 + r) * 131072 + s_l];
    {
        bf16x8 hv;
        #pragma unroll
        for (int r = 0; r < 8; ++r) hv[r] = sr[r];
        *(bf16x8*)(lds + swz(s_l, k8 * 8)) = hv;
    }

    #pragma unroll
    for (int t = 0; t < 4; ++t) {
        if (t < 3) {
            #pragma unroll
            for (int r = 0; r < 8; ++r)
                sr[r] = xslab[(size_t)((t + 1) * 64 + k8 * 8 + r) * 131072 + s_l];
        }
        __syncthreads();

        const char* bhib = lds + (t & 1) * 16384;
        #pragma unroll
        for (int kk = 0; kk < 2; ++kk) {
            const int idx = (wave * 8 + 2 * t + kk) * 64 + lane;
            const bf16x8 a1h = w1hf[idx];
            const bf16x8 a1l = w1lf[idx];
            #pragma unroll
            for (int j = 0; j < 8; ++j) {
                const int s = j * 16 + (lane & 15);
                const int k = kk * 32 + (lane >> 4) * 8;
                const bf16x8 bh = *(const bf16x8*)(bhib + swz(s, k));
                f32x4 c = acc[j];
                c = __builtin_amdgcn_mfma_f32_16x16x32_bf16(a1h, bh, c, 0, 0, 0);
                c = __builtin_amdgcn_mfma_f32_16x16x32_bf16(a1l, bh, c, 0, 0, 0);
                acc[j] = c;
            }
        }

        if (t < 3) {
            bf16x8 hv;
            #pragma unroll
            for (int r = 0; r < 8; ++r) hv[r] = sr[r];
            *(bf16x8*)(lds + ((t + 1) & 1) * 16384 + swz(s_l, k8 * 8)) = hv;
        }
    }

    // ---- phase B: a = relu(acc + b1), hi-only bf16 into [128 s][256 k] ----
    __syncthreads();
    {
        const int m4 = (lane >> 4) * 4;
        #pragma unroll
        for (int r = 0; r < 4; ++r) {
            const int o = wave * 16 + m4 + r;
            const float bv = b1[o];
            #pragma unroll
            for (int j = 0; j < 8; ++j) {
                const int s = j * 16 + (lane & 15);
                *(short*)(lds + swz512(s, o)) = f2bf(fmaxf(acc[j][r] + bv, 0.f));
            }
        }
    }
    __syncthreads();

    // ---- phase C: GEMM2 (a hi-only -> 2 MFMA per frag) ----
    f32x4 acc2[8];
    #pragma unroll
    for (int j = 0; j < 8; ++j) acc2[j] = (f32x4){0.f, 0.f, 0.f, 0.f};

    const bf16x8* w2hf = (const bf16x8*)w2hi;
    const bf16x8* w2lf = (const bf16x8*)w2lo;
    #pragma unroll
    for (int t2 = 0; t2 < 8; ++t2) {
        const int idx = (wave * 8 + t2) * 64 + lane;
        const bf16x8 a2h = w2hf[idx];
        const bf16x8 a2l = w2lf[idx];
        #pragma unroll
        for (int j = 0; j < 8; ++j) {
            const int s = j * 16 + (lane & 15);
            const int k = t2 * 32 + (lane >> 4) * 8;
            const bf16x8 bh = *(const bf16x8*)(lds + swz512(s, k));
            f32x4 c = acc2[j];
            c = __builtin_amdgcn_mfma_f32_16x16x32_bf16(a2h, bh, c, 0, 0, 0);
            c = __builtin_amdgcn_mfma_f32_16x16x32_bf16(a2l, bh, c, 0, 0, 0);
            acc2[j] = c;
        }
    }

    // ---- epilogue: direct fp32 stores ----
    float* ob = out + boff + sT;
    const int n_l = lane & 15;
    const int m4  = (lane >> 4) * 4;
    #pragma unroll
    for (int r = 0; r < 4; ++r) {
        const int o = wave * 16 + m4 + r;
        const float bv = b2[o];
        #pragma unroll
        for (int j = 0; j < 8; ++j)
            ob[(size_t)o * DHWC + j * 16 + n_l] = fmaxf(acc2[j][r] + bv, 0.f);
    }
}

// ---------------------------------------------------------------------------
// Pipeline: prep_w -> q=conv(eeg) ; {k,v}=kv_conv(img) -> attn -> tail.
// ws (u32): qpk[N] | kpk[N] | weights (shorts). attn overwrites kpk slabs
// with wv (bf16 shorts, slab layout). d_out: v (N shorts) during attn, then
// final fp32 output.
// ---------------------------------------------------------------------------
extern "C" void kernel_launch(void* const* d_in, const int* in_sizes, int n_in,
                              void* d_out, int out_size, void* d_ws, size_t ws_size,
                              hipStream_t stream)
{
    const float* eeg    = (const float*)d_in[0];
    const float* img    = (const float*)d_in[1];
    const float* q_w    = (const float*)d_in[2];
    const float* q_b    = (const float*)d_in[3];
    const float* k_w    = (const float*)d_in[4];
    const float* k_b    = (const float*)d_in[5];
    const float* v_w    = (const float*)d_in[6];
    const float* v_b    = (const float*)d_in[7];
    const float* attn_w = (const float*)d_in[8];
    const float* attn_b = (const float*)d_in[9];
    const float* out_w  = (const float*)d_in[10];
    const float* out_b  = (const float*)d_in[11];

    const size_t N = (size_t)NBC * CC * DHWC;
    unsigned* qpk = (unsigned*)d_ws;
    unsigned* kpk = qpk + N;
    short*    wsp = (short*)(kpk + N);
    short*    vsh = (short*)d_out;
    float*    outp = (float*)d_out;

    prep_w_kernel<<<dim3(16, 8, 5), dim3(64), 0, stream>>>(
        q_w, k_w, v_w, attn_w, out_w, wsp);

    const dim3 cgrid(DHWC / 128, NBC);

    conv_mfma_kernel<<<cgrid, dim3(1024), 0, stream>>>(
        eeg, wsp, wsp + 65536, q_b, qpk);

    kv_conv_kernel<<<cgrid, dim3(1024), 0, stream>>>(
        img, wsp + 131072, wsp + 131072 + 65536,
        wsp + 2 * 131072, wsp + 2 * 131072 + 65536,
        k_b, v_b, kpk, vsh);

    attn_mfma_kernel<<<dim3(NBC * CC * 16), dim3(256), 0, stream>>>(
        qpk, kpk, vsh, (short*)kpk);

    tail_fused_kernel<<<cgrid, dim3(1024), 0, stream>>>(
        (const short*)kpk,
        wsp + 3 * 131072, wsp + 3 * 131072 + 65536, attn_b,
        wsp + 4 * 131072, wsp + 4 * 131072 + 65536, out_b, outp);
}

// Round 15
// 362.455 us; speedup vs baseline: 1.0794x; 1.0794x over previous
//
#include <hip/hip_runtime.h>

#define CC   256
#define DHWC 65536          // D*H*W
#define NBC  2              // batch

typedef __attribute__((ext_vector_type(8))) short bf16x8;
typedef __attribute__((ext_vector_type(4))) short bf16x4;
typedef __attribute__((ext_vector_type(4))) float f32x4;

// ---- bf16 split helpers (branchless, bit-level, RTN-even) --------------------
__device__ __forceinline__ short f2bf(float x) {
    unsigned u = __builtin_bit_cast(unsigned, x);
    unsigned r = (u + 0x7fffu + ((u >> 16) & 1u)) >> 16;
    return (short)r;
}
__device__ __forceinline__ float bf2f(short h) {
    unsigned u = ((unsigned)(unsigned short)h) << 16;
    return __builtin_bit_cast(float, u);
}

// swizzled byte offset into a [R rows][64 c] bf16 LDS plane (row stride 128 B).
__device__ __forceinline__ int swz(int r, int c) {
    return (r * 128 + c * 2) ^ ((r & 7) << 4);
}
// richer swizzle for the V^T plane (write pattern is rows at stride 4)
__device__ __forceinline__ int vswz(int r, int c) {
    return (r * 128 + c * 2) ^ (((r ^ (r >> 3)) & 7) << 4);
}
// swizzled byte offset into a [128 s][256 k] bf16 LDS plane (row stride 512 B).
__device__ __forceinline__ int swz512(int s, int k) {
    return (s * 512 + k * 2) ^ ((s & 7) << 4);
}
// swizzled byte offset into a [256 rows][128 s] bf16 bounce plane (stride 256 B).
__device__ __forceinline__ int swz256(int r, int s) {
    return (r * 256 + s * 2) ^ ((r & 7) << 4);
}
// swizzled byte offset into a [128 rows][128 c] fp32 bounce plane (stride 512 B).
__device__ __forceinline__ int swzf(int r, int c) {
    return (r * 512 + c * 4) ^ ((r & 7) << 4);
}

// ---------------------------------------------------------------------------
// prep: split 5 weight matrices [256][256] fp32 into hi/lo bf16 planes stored
// fragment-major for mfma_f32_16x16x32_bf16 A-operand. Matrix m: hi at
// wsp + m*131072, lo at +65536.
// ---------------------------------------------------------------------------
__global__ void prep_w_kernel(const float* __restrict__ q_w, const float* __restrict__ k_w,
                              const float* __restrict__ v_w, const float* __restrict__ attn_w,
                              const float* __restrict__ out_w, short* __restrict__ wsp)
{
    const int l  = threadIdx.x;          // 64
    const int fo = blockIdx.x;           // 16
    const int t  = blockIdx.y;           // 8
    const int m  = blockIdx.z;           // 5
    const float* w = (m == 0) ? q_w : (m == 1) ? k_w : (m == 2) ? v_w
                   : (m == 3) ? attn_w : out_w;
    short* whi = wsp + (size_t)m * 131072;
    short* wlo = whi + 65536;

    const int o = fo * 16 + (l & 15);
    const int k = t * 32 + (l >> 4) * 8;

    bf16x8 hv, lv;
    #pragma unroll
    for (int r = 0; r < 8; ++r) {
        const float x = w[o * 256 + k + r];
        const short h = f2bf(x);
        hv[r] = h;
        lv[r] = f2bf(x - bf2f(h));
    }
    const int idx = (fo * 8 + t) * 64 + l;
    *(bf16x8*)(whi + idx * 8) = hv;
    *(bf16x8*)(wlo + idx * 8) = lv;
}

// ---------------------------------------------------------------------------
// conv1x1 (q), BN=128, 1024 thr = 16 waves, M=16 x N=128 wave tile.
// K-loop: loads issued AFTER the barrier (so the barrier's implicit
// vmcnt(0) drain never waits on them; latency hides under the MFMA phase).
// Direct fp32 store epilogue.
// ---------------------------------------------------------------------------
__global__ __launch_bounds__(1024, 4) void conv_mfma_kernel(
    const float* __restrict__ x, const short* __restrict__ whi,
    const short* __restrict__ wlo, const float* __restrict__ bias,
    float* __restrict__ out)
{
    __shared__ char lds[65536];

    const int tid  = threadIdx.x;
    const int lane = tid & 63;
    const int wave = tid >> 6;            // 0..15
    const size_t boff = (size_t)blockIdx.y * ((size_t)CC * DHWC);
    const int sT = blockIdx.x * 128;
    const float* xb = x + boff + sT;
    const bf16x8* whf = (const bf16x8*)whi;
    const bf16x8* wlf = (const bf16x8*)wlo;

    f32x4 acc[8];
    #pragma unroll
    for (int j = 0; j < 8; ++j) acc[j] = (f32x4){0.f, 0.f, 0.f, 0.f};

    const int s_l = tid & 127;
    const int k8  = tid >> 7;     // 0..7

    float xr[8];
    #pragma unroll
    for (int r = 0; r < 8; ++r)
        xr[r] = xb[(size_t)(k8 * 8 + r) * DHWC + s_l];
    {
        bf16x8 hv, lv;
        #pragma unroll
        for (int r = 0; r < 8; ++r) {
            const short h = f2bf(xr[r]);
            hv[r] = h;
            lv[r] = f2bf(xr[r] - bf2f(h));
        }
        const int off = swz(s_l, k8 * 8);
        *(bf16x8*)(lds + off) = hv;
        *(bf16x8*)(lds + 16384 + off) = lv;
    }

    #pragma unroll
    for (int t = 0; t < 4; ++t) {
        __syncthreads();
        if (t < 3) {                       // issue AFTER barrier: stays in flight
            #pragma unroll
            for (int r = 0; r < 8; ++r)
                xr[r] = xb[(size_t)((t + 1) * 64 + k8 * 8 + r) * DHWC + s_l];
        }

        const char* bhib = lds + (t & 1) * 32768;
        const char* blob = bhib + 16384;
        #pragma unroll
        for (int kk = 0; kk < 2; ++kk) {
            const int idx = (wave * 8 + 2 * t + kk) * 64 + lane;
            const bf16x8 a1h = whf[idx];
            const bf16x8 a1l = wlf[idx];
            #pragma unroll
            for (int j = 0; j < 8; ++j) {
                const int s = j * 16 + (lane & 15);
                const int k = kk * 32 + (lane >> 4) * 8;
                const bf16x8 bh = *(const bf16x8*)(bhib + swz(s, k));
                const bf16x8 bl = *(const bf16x8*)(blob + swz(s, k));
                f32x4 c = acc[j];
                c = __builtin_amdgcn_mfma_f32_16x16x32_bf16(a1h, bh, c, 0, 0, 0);
                c = __builtin_amdgcn_mfma_f32_16x16x32_bf16(a1h, bl, c, 0, 0, 0);
                c = __builtin_amdgcn_mfma_f32_16x16x32_bf16(a1l, bh, c, 0, 0, 0);
                acc[j] = c;
            }
        }

        if (t < 3) {
            bf16x8 hv, lv;
            #pragma unroll
            for (int r = 0; r < 8; ++r) {
                const short h = f2bf(xr[r]);
                hv[r] = h;
                lv[r] = f2bf(xr[r] - bf2f(h));
            }
            const int off = ((t + 1) & 1) * 32768 + swz(s_l, k8 * 8);
            *(bf16x8*)(lds + off) = hv;
            *(bf16x8*)(lds + 16384 + off) = lv;
        }
    }

    float* ob = out + boff + sT;
    const int n_l = lane & 15;
    const int m4  = (lane >> 4) * 4;
    #pragma unroll
    for (int r = 0; r < 4; ++r) {
        const int o = wave * 16 + m4 + r;
        const float bv = bias[o];
        #pragma unroll
        for (int j = 0; j < 8; ++j)
            ob[(size_t)o * DHWC + j * 16 + n_l] = acc[j][r] + bv;
    }
}

// ---------------------------------------------------------------------------
// kv conv, BN=128, loads-after-barrier K-loop. k fp32 via LDS bounce
// (2 halves of 128 rows); v shorts via LDS bounce.
// ---------------------------------------------------------------------------
__global__ __launch_bounds__(1024, 4) void kv_conv_kernel(
    const float* __restrict__ img,
    const short* __restrict__ wkhi, const short* __restrict__ wklo,
    const short* __restrict__ wvhi, const short* __restrict__ wvlo,
    const float* __restrict__ kb, const float* __restrict__ vb,
    float* __restrict__ kout, short* __restrict__ vout)
{
    __shared__ char lds[65536];

    const int tid  = threadIdx.x;
    const int lane = tid & 63;
    const int wave = tid >> 6;
    const size_t boff = (size_t)blockIdx.y * ((size_t)CC * DHWC);
    const int sT = blockIdx.x * 128;
    const float* xb = img + boff + sT;
    const bf16x8* wkhf = (const bf16x8*)wkhi;
    const bf16x8* wklf = (const bf16x8*)wklo;
    const bf16x8* wvhf = (const bf16x8*)wvhi;
    const bf16x8* wvlf = (const bf16x8*)wvlo;

    f32x4 acck[8], accv[8];
    #pragma unroll
    for (int j = 0; j < 8; ++j) {
        acck[j] = (f32x4){0.f, 0.f, 0.f, 0.f};
        accv[j] = (f32x4){0.f, 0.f, 0.f, 0.f};
    }

    const int s_l = tid & 127;
    const int k8  = tid >> 7;

    float xr[8];
    #pragma unroll
    for (int r = 0; r < 8; ++r)
        xr[r] = xb[(size_t)(k8 * 8 + r) * DHWC + s_l];
    {
        bf16x8 hv, lv;
        #pragma unroll
        for (int r = 0; r < 8; ++r) {
            const short h = f2bf(xr[r]);
            hv[r] = h;
            lv[r] = f2bf(xr[r] - bf2f(h));
        }
        const int off = swz(s_l, k8 * 8);
        *(bf16x8*)(lds + off) = hv;
        *(bf16x8*)(lds + 16384 + off) = lv;
    }

    #pragma unroll
    for (int t = 0; t < 4; ++t) {
        __syncthreads();
        if (t < 3) {                       // issue AFTER barrier
            #pragma unroll
            for (int r = 0; r < 8; ++r)
                xr[r] = xb[(size_t)((t + 1) * 64 + k8 * 8 + r) * DHWC + s_l];
        }

        const char* bhib = lds + (t & 1) * 32768;
        const char* blob = bhib + 16384;
        #pragma unroll
        for (int kk = 0; kk < 2; ++kk) {
            const int idx = (wave * 8 + 2 * t + kk) * 64 + lane;
            const bf16x8 akh = wkhf[idx];
            const bf16x8 akl = wklf[idx];
            const bf16x8 avh = wvhf[idx];
            const bf16x8 avl = wvlf[idx];
            #pragma unroll
            for (int j = 0; j < 8; ++j) {
                const int s = j * 16 + (lane & 15);
                const int k = kk * 32 + (lane >> 4) * 8;
                const bf16x8 bh = *(const bf16x8*)(bhib + swz(s, k));
                const bf16x8 bl = *(const bf16x8*)(blob + swz(s, k));
                f32x4 c = acck[j];
                c = __builtin_amdgcn_mfma_f32_16x16x32_bf16(akh, bh, c, 0, 0, 0);
                c = __builtin_amdgcn_mfma_f32_16x16x32_bf16(akh, bl, c, 0, 0, 0);
                c = __builtin_amdgcn_mfma_f32_16x16x32_bf16(akl, bh, c, 0, 0, 0);
                acck[j] = c;
                f32x4 d = accv[j];
                d = __builtin_amdgcn_mfma_f32_16x16x32_bf16(avh, bh, d, 0, 0, 0);
                d = __builtin_amdgcn_mfma_f32_16x16x32_bf16(avh, bl, d, 0, 0, 0);
                d = __builtin_amdgcn_mfma_f32_16x16x32_bf16(avl, bh, d, 0, 0, 0);
                accv[j] = d;
            }
        }

        if (t < 3) {
            bf16x8 hv, lv;
            #pragma unroll
            for (int r = 0; r < 8; ++r) {
                const short h = f2bf(xr[r]);
                hv[r] = h;
                lv[r] = f2bf(xr[r] - bf2f(h));
            }
            const int off = ((t + 1) & 1) * 32768 + swz(s_l, k8 * 8);
            *(bf16x8*)(lds + off) = hv;
            *(bf16x8*)(lds + 16384 + off) = lv;
        }
    }

    const int n_l = lane & 15;
    const int m4  = (lane >> 4) * 4;

    // ---- k epilogue: bounce fp32 through LDS, 2 halves of 128 rows ----
    float* ko = kout + boff + sT;
    #pragma unroll
    for (int h = 0; h < 2; ++h) {
        __syncthreads();
        if ((wave >> 3) == h) {
            #pragma unroll
            for (int r = 0; r < 4; ++r) {
                const int o = wave * 16 + m4 + r;
                const float kbv = kb[o];
                const int lr = o & 127;
                #pragma unroll
                for (int j = 0; j < 8; ++j)
                    *(float*)(lds + swzf(lr, j * 16 + n_l)) = acck[j][r] + kbv;
            }
        }
        __syncthreads();
        #pragma unroll
        for (int it = 0; it < 4; ++it) {
            const int lr = it * 32 + (tid >> 5);
            const int c4 = (tid & 31) * 4;
            const float4 vv = *(const float4*)(lds + swzf(lr, c4));
            *(float4*)(ko + (size_t)(h * 128 + lr) * DHWC + c4) = vv;
        }
    }

    // ---- v epilogue: LDS bounce -> 256B-contiguous short stores ----
    __syncthreads();
    #pragma unroll
    for (int r = 0; r < 4; ++r) {
        const int o = wave * 16 + m4 + r;
        const float vbv = vb[o];
        #pragma unroll
        for (int j = 0; j < 8; ++j)
            *(short*)(lds + swz256(o, j * 16 + n_l)) = f2bf(accv[j][r] + vbv);
    }
    __syncthreads();
    short* vo = vout + boff + sT;
    #pragma unroll
    for (int it = 0; it < 4; ++it) {
        const int row = it * 64 + wave * 4 + (lane >> 4);
        const int sc  = (lane & 15) * 8;        // 8 shorts = 16B
        const bf16x8 v8 = *(const bf16x8*)(lds + swz256(row, sc));
        *(bf16x8*)(vo + (size_t)row * DHWC + sc) = v8;
    }
}

// ---------------------------------------------------------------------------
// attention (round-11 verbatim). One block (256 thr = 4 waves) per slab.
// Coalesced q/k staging; wv written as bf16 shorts IN-PLACE over the slab's
// k storage via an LDS bounce.
// ---------------------------------------------------------------------------
__global__ __launch_bounds__(256, 4) void attn_mfma_kernel(
    const float* __restrict__ q, const float* kg,
    const short* __restrict__ vsh, short* wvk)
{
    __shared__ char lds[40960];
    const int QHI = 0, QLO = 8192, KHI = 16384, KLO = 24576, VT = 32768;

    const int tid  = threadIdx.x;
    const int lane = tid & 63;
    const int wsx  = tid >> 6;           // wave 0..3
    const size_t base = (size_t)blockIdx.x * 4096;

    {
        #pragma unroll
        for (int it = 0; it < 4; ++it) {
            const int r = it * 16 + (tid >> 4);
            const int c = (tid & 15) * 4;
            const float4 qa = *(const float4*)(q  + base + r * 64 + c);
            const float4 ka = *(const float4*)(kg + base + r * 64 + c);
            bf16x4 qh, ql, kh, kl;
            #pragma unroll
            for (int e = 0; e < 4; ++e) {
                const float xq = ((const float*)&qa)[e];
                short h = f2bf(xq); qh[e] = h; ql[e] = f2bf(xq - bf2f(h));
                const float xk = ((const float*)&ka)[e];
                h = f2bf(xk); kh[e] = h; kl[e] = f2bf(xk - bf2f(h));
            }
            const int off = swz(r, c);
            *(bf16x4*)(lds + QHI + off) = qh;
            *(bf16x4*)(lds + QLO + off) = ql;
            *(bf16x4*)(lds + KHI + off) = kh;
            *(bf16x4*)(lds + KLO + off) = kl;
        }
        const short* vpl = vsh + base;
        const int x0 = (tid >> 4) * 4;
        const int w0 = (tid & 15) * 4;
        bf16x4 vr[4];
        #pragma unroll
        for (int i = 0; i < 4; ++i)
            vr[i] = *(const bf16x4*)(vpl + (x0 + i) * 64 + w0);
        #pragma unroll
        for (int j = 0; j < 4; ++j) {
            bf16x4 tv;
            #pragma unroll
            for (int i = 0; i < 4; ++i) tv[i] = vr[i][j];
            *(bf16x4*)(lds + VT + vswz(w0 + j, x0)) = tv;
        }
    }
    __syncthreads();

    f32x4 acc[4];
    #pragma unroll
    for (int j = 0; j < 4; ++j) acc[j] = (f32x4){0.f, 0.f, 0.f, 0.f};

    const int arow = wsx * 16 + (lane & 15);
    #pragma unroll
    for (int kk = 0; kk < 2; ++kk) {
        const int kcol = kk * 32 + (lane >> 4) * 8;
        const bf16x8 aqh = *(const bf16x8*)(lds + QHI + swz(arow, kcol));
        const bf16x8 aql = *(const bf16x8*)(lds + QLO + swz(arow, kcol));
        #pragma unroll
        for (int j = 0; j < 4; ++j) {
            const int brow = j * 16 + (lane & 15);
            const bf16x8 bkh = *(const bf16x8*)(lds + KHI + swz(brow, kcol));
            const bf16x8 bkl = *(const bf16x8*)(lds + KLO + swz(brow, kcol));
            f32x4 c = acc[j];
            c = __builtin_amdgcn_mfma_f32_16x16x32_bf16(aqh, bkh, c, 0, 0, 0);
            c = __builtin_amdgcn_mfma_f32_16x16x32_bf16(aqh, bkl, c, 0, 0, 0);
            c = __builtin_amdgcn_mfma_f32_16x16x32_bf16(aql, bkh, c, 0, 0, 0);
            acc[j] = c;
        }
    }

    float p[4][4], invs[4];
    #pragma unroll
    for (int r = 0; r < 4; ++r) {
        float m = fmaxf(fmaxf(acc[0][r], acc[1][r]), fmaxf(acc[2][r], acc[3][r]));
        m = fmaxf(m, __shfl_xor(m, 1));
        m = fmaxf(m, __shfl_xor(m, 2));
        m = fmaxf(m, __shfl_xor(m, 4));
        m = fmaxf(m, __shfl_xor(m, 8));
        float s = 0.f;
        #pragma unroll
        for (int j = 0; j < 4; ++j) { p[j][r] = __expf(acc[j][r] - m); s += p[j][r]; }
        s += __shfl_xor(s, 1);
        s += __shfl_xor(s, 2);
        s += __shfl_xor(s, 4);
        s += __shfl_xor(s, 8);
        invs[r] = 1.f / s;
    }

    __syncthreads();

    #pragma unroll
    for (int r = 0; r < 4; ++r) {
        const int row = wsx * 16 + (lane >> 4) * 4 + r;
        #pragma unroll
        for (int j = 0; j < 4; ++j) {
            const int col = j * 16 + (lane & 15);
            *(short*)(lds + QHI + swz(row, col)) = f2bf(p[j][r]);
        }
    }
    __syncthreads();

    f32x4 o_[4];
    #pragma unroll
    for (int j = 0; j < 4; ++j) o_[j] = (f32x4){0.f, 0.f, 0.f, 0.f};

    #pragma unroll
    for (int kk = 0; kk < 2; ++kk) {
        const int kcol = kk * 32 + (lane >> 4) * 8;
        const bf16x8 aph = *(const bf16x8*)(lds + QHI + swz(arow, kcol));
        #pragma unroll
        for (int j = 0; j < 4; ++j) {
            const int brow = j * 16 + (lane & 15);
            const bf16x8 bvh = *(const bf16x8*)(lds + VT + vswz(brow, kcol));
            o_[j] = __builtin_amdgcn_mfma_f32_16x16x32_bf16(aph, bvh, o_[j], 0, 0, 0);
        }
    }

    // ---- epilogue: wv bf16 shorts -> bounce via QHI plane -> k slab ----
    __syncthreads();
    #pragma unroll
    for (int r = 0; r < 4; ++r) {
        const int h = wsx * 16 + (lane >> 4) * 4 + r;
        #pragma unroll
        for (int j = 0; j < 4; ++j)
            *(short*)(lds + QHI + swz(h, j * 16 + (lane & 15))) = f2bf(o_[j][r] * invs[r]);
    }
    __syncthreads();
    short* wvo = wvk + (size_t)blockIdx.x * 8192;   // slab owns 8192 shorts of kbuf
    #pragma unroll
    for (int it = 0; it < 4; ++it) {
        const int row = it * 16 + (tid >> 4);
        const int sc  = (tid & 15) * 4;             // 4 shorts = 8B
        const bf16x4 v4 = *(const bf16x4*)(lds + QHI + swz(row, sc));
        *(bf16x4*)(wvo + (size_t)row * 64 + sc) = v4;
    }
}

// ---------------------------------------------------------------------------
// fused tail: out = relu(W2 * relu(W1 * wv + b1) + b2). wv arrives as bf16
// shorts in SLAB layout inside kbuf (channel stride 131072 shorts).
// Loads-after-barrier K-loop; hi-only staging, 2-MFMA GEMM1; phase B hi-only
// a; 2-MFMA GEMM2; direct-store fp32 epilogue.
// ---------------------------------------------------------------------------
__global__ __launch_bounds__(1024, 4) void tail_fused_kernel(
    const short* __restrict__ xs,
    const short* __restrict__ w1hi, const short* __restrict__ w1lo,
    const float* __restrict__ b1,
    const short* __restrict__ w2hi, const short* __restrict__ w2lo,
    const float* __restrict__ b2,
    float* __restrict__ out)
{
    __shared__ char lds[65536];

    const int tid  = threadIdx.x;
    const int lane = tid & 63;
    const int wave = tid >> 6;
    const size_t boff = (size_t)blockIdx.y * ((size_t)CC * DHWC);
    const int sT = blockIdx.x * 128;
    const bf16x8* w1hf = (const bf16x8*)w1hi;
    const bf16x8* w1lf = (const bf16x8*)w1lo;

    f32x4 acc[8];
    #pragma unroll
    for (int j = 0; j < 8; ++j) acc[j] = (f32x4){0.f, 0.f, 0.f, 0.f};

    const int s_l = tid & 127;
    const int k8  = tid >> 7;

    // slab-layout base for this (batch, spatial tile): channel stride 131072
    const short* xslab = xs + (size_t)blockIdx.y * 33554432
                            + (size_t)(sT >> 12) * 8192 + (sT & 4095);

    short sr[8];
    #pragma unroll
    for (int r = 0; r < 8; ++r)
        sr[r] = xslab[(size_t)(k8 * 8 + r) * 131072 + s_l];
    {
        bf16x8 hv;
        #pragma unroll
        for (int r = 0; r < 8; ++r) hv[r] = sr[r];
        *(bf16x8*)(lds + swz(s_l, k8 * 8)) = hv;
    }

    #pragma unroll
    for (int t = 0; t < 4; ++t) {
        __syncthreads();
        if (t < 3) {                       // issue AFTER barrier
            #pragma unroll
            for (int r = 0; r < 8; ++r)
                sr[r] = xslab[(size_t)((t + 1) * 64 + k8 * 8 + r) * 131072 + s_l];
        }

        const char* bhib = lds + (t & 1) * 16384;
        #pragma unroll
        for (int kk = 0; kk < 2; ++kk) {
            const int idx = (wave * 8 + 2 * t + kk) * 64 + lane;
            const bf16x8 a1h = w1hf[idx];
            const bf16x8 a1l = w1lf[idx];
            #pragma unroll
            for (int j = 0; j < 8; ++j) {
                const int s = j * 16 + (lane & 15);
                const int k = kk * 32 + (lane >> 4) * 8;
                const bf16x8 bh = *(const bf16x8*)(bhib + swz(s, k));
                f32x4 c = acc[j];
                c = __builtin_amdgcn_mfma_f32_16x16x32_bf16(a1h, bh, c, 0, 0, 0);
                c = __builtin_amdgcn_mfma_f32_16x16x32_bf16(a1l, bh, c, 0, 0, 0);
                acc[j] = c;
            }
        }

        if (t < 3) {
            bf16x8 hv;
            #pragma unroll
            for (int r = 0; r < 8; ++r) hv[r] = sr[r];
            *(bf16x8*)(lds + ((t + 1) & 1) * 16384 + swz(s_l, k8 * 8)) = hv;
        }
    }

    // ---- phase B: a = relu(acc + b1), hi-only bf16 into [128 s][256 k] ----
    __syncthreads();
    {
        const int m4 = (lane >> 4) * 4;
        #pragma unroll
        for (int r = 0; r < 4; ++r) {
            const int o = wave * 16 + m4 + r;
            const float bv = b1[o];
            #pragma unroll
            for (int j = 0; j < 8; ++j) {
                const int s = j * 16 + (lane & 15);
                *(short*)(lds + swz512(s, o)) = f2bf(fmaxf(acc[j][r] + bv, 0.f));
            }
        }
    }
    __syncthreads();

    // ---- phase C: GEMM2 (a hi-only -> 2 MFMA per frag) ----
    f32x4 acc2[8];
    #pragma unroll
    for (int j = 0; j < 8; ++j) acc2[j] = (f32x4){0.f, 0.f, 0.f, 0.f};

    const bf16x8* w2hf = (const bf16x8*)w2hi;
    const bf16x8* w2lf = (const bf16x8*)w2lo;
    #pragma unroll
    for (int t2 = 0; t2 < 8; ++t2) {
        const int idx = (wave * 8 + t2) * 64 + lane;
        const bf16x8 a2h = w2hf[idx];
        const bf16x8 a2l = w2lf[idx];
        #pragma unroll
        for (int j = 0; j < 8; ++j) {
            const int s = j * 16 + (lane & 15);
            const int k = t2 * 32 + (lane >> 4) * 8;
            const bf16x8 bh = *(const bf16x8*)(lds + swz512(s, k));
            f32x4 c = acc2[j];
            c = __builtin_amdgcn_mfma_f32_16x16x32_bf16(a2h, bh, c, 0, 0, 0);
            c = __builtin_amdgcn_mfma_f32_16x16x32_bf16(a2l, bh, c, 0, 0, 0);
            acc2[j] = c;
        }
    }

    // ---- epilogue: direct fp32 stores ----
    float* ob = out + boff + sT;
    const int n_l = lane & 15;
    const int m4  = (lane >> 4) * 4;
    #pragma unroll
    for (int r = 0; r < 4; ++r) {
        const int o = wave * 16 + m4 + r;
        const float bv = b2[o];
        #pragma unroll
        for (int j = 0; j < 8; ++j)
            ob[(size_t)o * DHWC + j * 16 + n_l] = fmaxf(acc2[j][r] + bv, 0.f);
    }
}

// ---------------------------------------------------------------------------
// Pipeline: prep_w -> q=conv(eeg) ; {k,v}=kv_conv(img) -> attn -> tail.
// ws: qbuf (N f32) | kbuf (N f32; attn overwrites each slab with wv bf16
// shorts in-place) | weights. d_out: v (N shorts) during attn, then final out.
// ---------------------------------------------------------------------------
extern "C" void kernel_launch(void* const* d_in, const int* in_sizes, int n_in,
                              void* d_out, int out_size, void* d_ws, size_t ws_size,
                              hipStream_t stream)
{
    const float* eeg    = (const float*)d_in[0];
    const float* img    = (const float*)d_in[1];
    const float* q_w    = (const float*)d_in[2];
    const float* q_b    = (const float*)d_in[3];
    const float* k_w    = (const float*)d_in[4];
    const float* k_b    = (const float*)d_in[5];
    const float* v_w    = (const float*)d_in[6];
    const float* v_b    = (const float*)d_in[7];
    const float* attn_w = (const float*)d_in[8];
    const float* attn_b = (const float*)d_in[9];
    const float* out_w  = (const float*)d_in[10];
    const float* out_b  = (const float*)d_in[11];

    const size_t N = (size_t)NBC * CC * DHWC;
    float* qbuf = (float*)d_ws;
    float* kbuf = qbuf + N;
    short* wsp  = (short*)(kbuf + N);
    short* vsh  = (short*)d_out;
    float* outp = (float*)d_out;

    prep_w_kernel<<<dim3(16, 8, 5), dim3(64), 0, stream>>>(
        q_w, k_w, v_w, attn_w, out_w, wsp);

    const dim3 cgrid(DHWC / 128, NBC);

    conv_mfma_kernel<<<cgrid, dim3(1024), 0, stream>>>(
        eeg, wsp, wsp + 65536, q_b, qbuf);

    kv_conv_kernel<<<cgrid, dim3(1024), 0, stream>>>(
        img, wsp + 131072, wsp + 131072 + 65536,
        wsp + 2 * 131072, wsp + 2 * 131072 + 65536,
        k_b, v_b, kbuf, vsh);

    attn_mfma_kernel<<<dim3(NBC * CC * 16), dim3(256), 0, stream>>>(
        qbuf, kbuf, vsh, (short*)kbuf);

    tail_fused_kernel<<<cgrid, dim3(1024), 0, stream>>>(
        (const short*)kbuf,
        wsp + 3 * 131072, wsp + 3 * 131072 + 65536, attn_b,
        wsp + 4 * 131072, wsp + 4 * 131072 + 65536, out_b, outp);
}